// Round 2
// baseline (486.830 us; speedup 1.0000x reference)
//
#include <hip/hip_runtime.h>
#include <hip/hip_bf16.h>

// TransformerBlock fused kernel for MI355X (gfx950) — v2.1: occupancy restructure.
// Shapes: B=1024, T=128, D=128, H=4, HD=32, FF=512.
// One block per batch element; 512 threads = 8 waves; __launch_bounds__(512,4)
// caps VGPR at 128 so 2 blocks (16 waves) co-reside per CU (LDS = 65,536 B).
//
// Design (vs v1 @ 139 KB LDS / 1 block/CU):
//  - Swapped QK^T: S^T = mfma(K_frag, Q_frag) -> each lane owns a full score
//    row; softmax reduce = 2 shuffles; causal mask lane-local.
//  - P repacked to MFMA A-frags fully in-register (cross-quad shuffle),
//    no P LDS buffer, no per-head P barriers.
//  - Per-head K_h [128][40] / V_h^T [32][128] staged from hs (LN1 output);
//    Q kept in registers as 4 per-head B-frags (built once via same shuffle).
//  - Per-head Wo partial: x1 += attn_h @ Wo_h^T (k=32) via per-wave 16x40
//    LDS bounce; x1 residual stays in f32 registers; LN2 fully in-register.
//  - hs/h2/G: [128][128] bf16 with XOR granule swizzle (g ^= row&7) ->
//    conflict-free GEMM-pattern ds_read_b128 without pitch padding.
//  - Epilogue: x1 regs -> 64 KB f32 LDS overlay -> add to FF output.
// MFMA 16x16x32 bf16. A-frag: A[m=lane&15][k=quad*8+j]; B-frag:
// B[k=quad*8+j][n=lane&15]; C/D: col=lane&15, row=quad*4+reg (learn_hip m89/m91).
//
// v2.1: __has_builtin guards around exp2/rcp builtins (toolchain robustness).

typedef short bf16x8 __attribute__((ext_vector_type(8)));   // 8 bf16 in 4 VGPRs
typedef float f32x4  __attribute__((ext_vector_type(4)));
typedef unsigned short u16;
typedef unsigned int   u32;

#define TT   128
#define DDIM 128
#define FFD  512
#define KPIT 40    // K_h / bounce row pitch in u16 (80 B: 16B-aligned, 2-way banks)

// SCALE * log2(e): softmax done in exp2 domain with Q pre-scaled.
#define QSCALE 0.12751743f

#if defined(__has_builtin)
#if __has_builtin(__builtin_amdgcn_exp2f)
#define EXP2F(x) __builtin_amdgcn_exp2f(x)
#else
#define EXP2F(x) exp2f(x)
#endif
#if __has_builtin(__builtin_amdgcn_rcpf)
#define RCPF(x) __builtin_amdgcn_rcpf(x)
#else
#define RCPF(x) (1.0f / (x))
#endif
#else
#define EXP2F(x) exp2f(x)
#define RCPF(x) (1.0f / (x))
#endif

__device__ __forceinline__ u16 f2b(float f) {
    __hip_bfloat16 h = __float2bfloat16(f);   // RNE
    return __builtin_bit_cast(u16, h);
}
__device__ __forceinline__ u32 pk2(float x, float y) {
    return (u32)f2b(x) | ((u32)f2b(y) << 16);
}
__device__ __forceinline__ bf16x8 ldfrag(const u16* p) {  // LDS, 16B-aligned
    return __builtin_bit_cast(bf16x8, *reinterpret_cast<const uint4*>(p));
}
// Load 8 f32 from global, round to bf16 fragment (16B-aligned base).
__device__ __forceinline__ bf16x8 ldfrag_f32(const float* p) {
    float4 a = *reinterpret_cast<const float4*>(p);
    float4 b = *reinterpret_cast<const float4*>(p + 4);
    bf16x8 r;
    r[0] = (short)f2b(a.x); r[1] = (short)f2b(a.y);
    r[2] = (short)f2b(a.z); r[3] = (short)f2b(a.w);
    r[4] = (short)f2b(b.x); r[5] = (short)f2b(b.y);
    r[6] = (short)f2b(b.z); r[7] = (short)f2b(b.w);
    return r;
}
__device__ __forceinline__ f32x4 mfma16(bf16x8 a, bf16x8 b, f32x4 c) {
    return __builtin_amdgcn_mfma_f32_16x16x32_bf16(a, b, c, 0, 0, 0);
}
// Swizzled [128][128] bf16 tile: byte = row*256 + ((cg ^ (row&7))*16) + (col&7)*2
__device__ __forceinline__ bf16x8 ld_sw(const u16* base, int row, int cg) {
    return ldfrag(base + row * 128 + ((cg ^ (row & 7)) * 8));
}
__device__ __forceinline__ void st_sw(u16* base, int row, int col, u16 v) {
    base[row * 128 + (((col >> 3) ^ (row & 7)) * 8) + (col & 7)] = v;
}

// Cross-quad repack: input vals[i][r] = V[row][i*16 + quad*4 + r] (C-layout
// columns of this lane's row), output fr[g][j] = bf16(V[row][g*32 + quad*8 + j])
// (A/B-frag layout). Row (= lane&15) is preserved; only quad-dim moves.
// Derivation: c32 bits b4..b0; src lane quad=(b3,b2), reg=(b4,b1,b0);
// dst lane quad=(b4,b3), reg=(b2,b1,b0). => dst dword (d1,d0) at lane
// (lq,l4',l5') = D[l5'][d0] from lane lq + 16*d1 + 32*l4',
// with D[par][d0] = pack(vals[2g+par][2*d0], vals[2g+par][2*d0+1]).
__device__ __forceinline__ void quad_collect(const float (&vals)[8][4],
                                             bf16x8 (&fr)[4], int lane) {
    const int srcA = (lane & 15) + ((lane & 16) << 1);  // lq + 32*l4'
    const int srcB = srcA + 16;
    const bool hi = (lane & 32) != 0;                   // l5'
    #pragma unroll
    for (int g = 0; g < 4; g++) {
        u32 D00 = pk2(vals[2*g][0],     vals[2*g][1]);
        u32 D01 = pk2(vals[2*g][2],     vals[2*g][3]);
        u32 D10 = pk2(vals[2*g + 1][0], vals[2*g + 1][1]);
        u32 D11 = pk2(vals[2*g + 1][2], vals[2*g + 1][3]);
        u32 a00 = (u32)__shfl((int)D00, srcA);
        u32 a10 = (u32)__shfl((int)D10, srcA);
        u32 a01 = (u32)__shfl((int)D01, srcA);
        u32 a11 = (u32)__shfl((int)D11, srcA);
        u32 b00 = (u32)__shfl((int)D00, srcB);
        u32 b10 = (u32)__shfl((int)D10, srcB);
        u32 b01 = (u32)__shfl((int)D01, srcB);
        u32 b11 = (u32)__shfl((int)D11, srcB);
        uint4 q;
        q.x = hi ? a10 : a00;
        q.y = hi ? a11 : a01;
        q.z = hi ? b10 : b00;
        q.w = hi ? b11 : b01;
        fr[g] = __builtin_bit_cast(bf16x8, q);
    }
}

__global__ __launch_bounds__(512, 4) void tblock_kernel(
    const float* __restrict__ x,
    const float* __restrict__ ln1g, const float* __restrict__ ln1b,
    const float* __restrict__ Wq,   const float* __restrict__ Wk, const float* __restrict__ Wv,
    const float* __restrict__ Wo,   const float* __restrict__ bo,
    const float* __restrict__ ln2g, const float* __restrict__ ln2b,
    const float* __restrict__ W1,   const float* __restrict__ b1,
    const float* __restrict__ W2,   const float* __restrict__ b2,
    float* __restrict__ out)
{
    // 65,536 B total: bufH [128][128] swizzled (hs -> h2);
    // r2: during attn {Kh [128][40], Vth [32][128] swz, bounce 8x[16][40]},
    //     during FF G [128][128] swizzled.
    // Epilogue overlays whole sm as f32[128][128] (x1 bounce).
    __shared__ __align__(16) u16 sm[32768];
    u16* bufH = sm;
    u16* r2   = sm + 16384;
    u16* Kh   = r2;                   // 128*40 = 5120 u16
    u16* Vth  = r2 + 5120;            // 32*128 = 4096 u16
    u16* bnc  = r2 + 5120 + 4096;     // 8*16*40 = 5120 u16

    const int b    = blockIdx.x;
    const int tid  = threadIdx.x;
    const int w    = tid >> 6;     // wave id 0..7 (owns t-rows [w*16, w*16+16))
    const int l    = tid & 63;
    const int lq   = l & 15;
    const int quad = l >> 4;
    const float* xb = x + (size_t)b * (TT * DDIM);

    // ---------------- P0: LN1(x) -> bufH (bf16, swizzled) ----------------
    {
        const int row = tid >> 2, part = tid & 3;
        const float* src = xb + row * DDIM + part * 32;
        float v[32];
        float s = 0.f, s2 = 0.f;
        #pragma unroll
        for (int i = 0; i < 8; i++) {
            float4 u = *reinterpret_cast<const float4*>(src + i * 4);
            v[i * 4 + 0] = u.x; v[i * 4 + 1] = u.y;
            v[i * 4 + 2] = u.z; v[i * 4 + 3] = u.w;
            s  += u.x + u.y + u.z + u.w;
            s2 += u.x * u.x + u.y * u.y + u.z * u.z + u.w * u.w;
        }
        s  += __shfl_xor(s, 1);  s2 += __shfl_xor(s2, 1);
        s  += __shfl_xor(s, 2);  s2 += __shfl_xor(s2, 2);
        float mean = s * (1.f / 128.f);
        float var  = fmaxf(s2 * (1.f / 128.f) - mean * mean, 0.f);
        float rstd = rsqrtf(var + 1e-5f);
        #pragma unroll
        for (int i = 0; i < 4; i++) {
            u32 o4[4];
            #pragma unroll
            for (int j = 0; j < 4; j++) {
                int c = part * 32 + i * 8 + 2 * j;
                float r0 = (v[i * 8 + 2 * j]     - mean) * rstd * ln1g[c]     + ln1b[c];
                float r1 = (v[i * 8 + 2 * j + 1] - mean) * rstd * ln1g[c + 1] + ln1b[c + 1];
                o4[j] = (u32)f2b(r0) | ((u32)f2b(r1) << 16);
            }
            uint4 pkv; pkv.x = o4[0]; pkv.y = o4[1]; pkv.z = o4[2]; pkv.w = o4[3];
            int g = (part * 4 + i) ^ (row & 7);
            *reinterpret_cast<uint4*>(bufH + row * 128 + g * 8) = pkv;
        }
    }
    __syncthreads();

    // ---------------- P1: Q (pre-scaled) -> per-head register B-frags ----------------
    // Compute Q^T columns for OWN t-tile: mfma(a=Wq rows, b=hs rows w*16..).
    // C gives Q[t=w16+lq][o=mt*16+quad*4+r]; quad_collect -> per-head frags.
    bf16x8 qf0, qf1, qf2, qf3;
    {
        bf16x8 hf[4];
        #pragma unroll
        for (int ks = 0; ks < 4; ks++) hf[ks] = ld_sw(bufH, w * 16 + lq, ks * 4 + quad);
        float qt[8][4];
        #pragma unroll
        for (int mt = 0; mt < 8; mt++) {
            f32x4 acc = {0, 0, 0, 0};
            #pragma unroll
            for (int ks = 0; ks < 4; ks++) {
                bf16x8 a = ldfrag_f32(Wq + (mt * 16 + lq) * DDIM + ks * 32 + quad * 8);
                acc = mfma16(a, hf[ks], acc);
            }
            #pragma unroll
            for (int r = 0; r < 4; r++) qt[mt][r] = acc[r] * QSCALE;
        }
        bf16x8 qfr[4];
        quad_collect(qt, qfr, l);
        qf0 = qfr[0]; qf1 = qfr[1]; qf2 = qfr[2]; qf3 = qfr[3];
    }

    // x1 residual accumulator: (t = w*16+quad*4+r, d = nt*16+lq), f32.
    f32x4 x1acc[8];
    #pragma unroll
    for (int i = 0; i < 8; i++) x1acc[i] = f32x4{0, 0, 0, 0};

    // ---------------- P2: per-head attention ----------------
    #pragma unroll 1
    for (int h = 0; h < 4; h++) {
        // --- stage K_h: [t][hd] pitch 40 (wave computes own t rows) ---
        {
            bf16x8 hf[4];
            #pragma unroll
            for (int ks = 0; ks < 4; ks++) hf[ks] = ld_sw(bufH, w * 16 + lq, ks * 4 + quad);
            #pragma unroll
            for (int nt2 = 0; nt2 < 2; nt2++) {
                f32x4 acc = {0, 0, 0, 0};
                #pragma unroll
                for (int ks = 0; ks < 4; ks++) {
                    bf16x8 bwk = ldfrag_f32(Wk + (h * 32 + nt2 * 16 + lq) * DDIM + ks * 32 + quad * 8);
                    acc = mfma16(hf[ks], bwk, acc);
                }
                #pragma unroll
                for (int r = 0; r < 4; r++)
                    Kh[(w * 16 + quad * 4 + r) * KPIT + nt2 * 16 + lq] = f2b(acc[r]);
            }
        }
        // --- stage V_h^T: [o32][t] swizzled (waves split o-halves x t-pairs) ---
        {
            bf16x8 af[4];
            #pragma unroll
            for (int ks = 0; ks < 4; ks++)
                af[ks] = ldfrag_f32(Wv + (h * 32 + (w >> 2) * 16 + lq) * DDIM + ks * 32 + quad * 8);
            #pragma unroll
            for (int j2 = 0; j2 < 2; j2++) {
                int nt = 2 * (w & 3) + j2;
                f32x4 acc = {0, 0, 0, 0};
                #pragma unroll
                for (int ks = 0; ks < 4; ks++) {
                    bf16x8 bh = ld_sw(bufH, nt * 16 + lq, ks * 4 + quad);
                    acc = mfma16(af[ks], bh, acc);
                }
                #pragma unroll
                for (int r = 0; r < 4; r++)
                    st_sw(Vth, (w >> 2) * 16 + quad * 4 + r, nt * 16 + lq, f2b(acc[r]));
            }
        }
        __syncthreads();

        // --- S^T = mfma(K_frag, Q_frag): p[ns][r] = S[t=w16+lq][s=ns*16+quad*4+r] ---
        bf16x8 qh = (h == 0) ? qf0 : (h == 1) ? qf1 : (h == 2) ? qf2 : qf3;
        float p[8][4];
        #pragma unroll
        for (int ns = 0; ns < 8; ns++) {
            bf16x8 a = ldfrag(Kh + (ns * 16 + lq) * KPIT + quad * 8);
            f32x4 s4 = mfma16(a, qh, f32x4{0, 0, 0, 0});
            #pragma unroll
            for (int r = 0; r < 4; r++) p[ns][r] = s4[r];
        }
        // --- softmax (exp2 domain; Q pre-scaled by SCALE*log2e), causal mask ---
        const int trow = w * 16 + lq;
        float mx = -3.0e38f;
        #pragma unroll
        for (int ns = 0; ns < 8; ns++) {
            #pragma unroll
            for (int r = 0; r < 4; r++) {
                int sidx = ns * 16 + quad * 4 + r;
                mx = (sidx <= trow) ? fmaxf(mx, p[ns][r]) : mx;
            }
        }
        mx = fmaxf(mx, __shfl_xor(mx, 16));
        mx = fmaxf(mx, __shfl_xor(mx, 32));
        float sum = 0.f;
        #pragma unroll
        for (int ns = 0; ns < 8; ns++) {
            #pragma unroll
            for (int r = 0; r < 4; r++) {
                int sidx = ns * 16 + quad * 4 + r;
                float e = (sidx <= trow) ? EXP2F(p[ns][r] - mx) : 0.f;
                p[ns][r] = e; sum += e;
            }
        }
        sum += __shfl_xor(sum, 16);
        sum += __shfl_xor(sum, 32);
        float inv = RCPF(sum);   // sum >= 1 (max lane contributes exp2(0)=1)
        #pragma unroll
        for (int ns = 0; ns < 8; ns++)
            #pragma unroll
            for (int r = 0; r < 4; r++) p[ns][r] *= inv;

        // --- P -> A-frags in-register; attn_h = P @ V_h ---
        bf16x8 pfr[4];
        quad_collect(p, pfr, l);
        f32x4 av0 = {0, 0, 0, 0}, av1 = {0, 0, 0, 0};
        #pragma unroll
        for (int ks = 0; ks < 4; ks++) {
            int g8 = ((ks * 4 + quad) ^ (lq & 7)) * 8;
            av0 = mfma16(pfr[ks], ldfrag(Vth + lq * 128 + g8), av0);
            av1 = mfma16(pfr[ks], ldfrag(Vth + (16 + lq) * 128 + g8), av1);
        }
        // --- per-wave bounce (C-layout -> A-frag) + Wo_h partial into x1acc ---
        u16* bw_ = bnc + w * (16 * KPIT);
        #pragma unroll
        for (int r = 0; r < 4; r++) {
            bw_[(quad * 4 + r) * KPIT + lq]      = f2b(av0[r]);
            bw_[(quad * 4 + r) * KPIT + 16 + lq] = f2b(av1[r]);
        }
        asm volatile("s_waitcnt lgkmcnt(0)" ::: "memory");   // intra-wave LDS RAW
        __builtin_amdgcn_sched_barrier(0);
        bf16x8 pa = ldfrag(bw_ + lq * KPIT + quad * 8);
        #pragma unroll
        for (int nt = 0; nt < 8; nt++) {
            bf16x8 wo = ldfrag_f32(Wo + (nt * 16 + lq) * DDIM + h * 32 + quad * 8);
            x1acc[nt] = mfma16(pa, wo, x1acc[nt]);
        }
        __syncthreads();   // Kh/Vth consumed; next head may overwrite
    }

    // ---------------- P3: x1 = x + attn@Wo^T + bo (in regs) ----------------
    #pragma unroll
    for (int nt = 0; nt < 8; nt++) {
        float bov = bo[nt * 16 + lq];
        #pragma unroll
        for (int r = 0; r < 4; r++)
            x1acc[nt][r] += xb[(w * 16 + quad * 4 + r) * DDIM + nt * 16 + lq] + bov;
    }

    // ---------------- P4: LN2 in-register -> h2 into bufH ----------------
    {
        float s[4] = {0, 0, 0, 0}, s2[4] = {0, 0, 0, 0};
        #pragma unroll
        for (int nt = 0; nt < 8; nt++) {
            #pragma unroll
            for (int r = 0; r < 4; r++) {
                float v = x1acc[nt][r];
                s[r] += v; s2[r] += v * v;
            }
        }
        float mean_[4], rstd_[4];
        #pragma unroll
        for (int r = 0; r < 4; r++) {
            #pragma unroll
            for (int m_ = 1; m_ <= 8; m_ <<= 1) {
                s[r]  += __shfl_xor(s[r],  m_);
                s2[r] += __shfl_xor(s2[r], m_);
            }
            mean_[r] = s[r] * (1.f / 128.f);
            float var = fmaxf(s2[r] * (1.f / 128.f) - mean_[r] * mean_[r], 0.f);
            rstd_[r] = rsqrtf(var + 1e-5f);
        }
        #pragma unroll
        for (int nt = 0; nt < 8; nt++) {
            int d = nt * 16 + lq;
            float gg = ln2g[d], bb = ln2b[d];
            #pragma unroll
            for (int r = 0; r < 4; r++) {
                int t2 = w * 16 + quad * 4 + r;
                st_sw(bufH, t2, d, f2b((x1acc[nt][r] - mean_[r]) * rstd_[r] * gg + bb));
            }
        }
    }
    __syncthreads();

    // ---------------- P5: FF, register accumulation over f-chunks ----------------
    f32x4 oacc[8];
    #pragma unroll
    for (int i = 0; i < 8; i++) oacc[i] = f32x4{0, 0, 0, 0};

    #pragma unroll 1
    for (int fc = 0; fc < 4; fc++) {
        const int fbase = fc * 128;
        // G = relu(h2 @ W1c^T + b1) -> r2 (swizzled)
        bf16x8 wf1[4];
        #pragma unroll
        for (int ks = 0; ks < 4; ks++)
            wf1[ks] = ldfrag_f32(W1 + (fbase + w * 16 + lq) * DDIM + ks * 32 + quad * 8);
        const float b1v = b1[fbase + w * 16 + lq];
        #pragma unroll
        for (int m = 0; m < 8; m++) {
            f32x4 acc = {0, 0, 0, 0};
            #pragma unroll
            for (int ks = 0; ks < 4; ks++)
                acc = mfma16(ld_sw(bufH, m * 16 + lq, ks * 4 + quad), wf1[ks], acc);
            #pragma unroll
            for (int r = 0; r < 4; r++) {
                int t2 = m * 16 + quad * 4 + r;
                float gv = acc[r] + b1v;
                gv = gv > 0.f ? gv : 0.f;
                st_sw(r2, t2, w * 16 + lq, f2b(gv));
            }
        }
        __syncthreads();
        // oacc += G @ W2c^T  (wave owns d-cols w*16..)
        bf16x8 wf2[4];
        #pragma unroll
        for (int ks = 0; ks < 4; ks++)
            wf2[ks] = ldfrag_f32(W2 + (w * 16 + lq) * FFD + fbase + ks * 32 + quad * 8);
        #pragma unroll
        for (int m = 0; m < 8; m++) {
            #pragma unroll
            for (int ks = 0; ks < 4; ks++)
                oacc[m] = mfma16(ld_sw(r2, m * 16 + lq, ks * 4 + quad), wf2[ks], oacc[m]);
        }
        __syncthreads();
    }

    // ---------------- P6: x1 layout bounce (f32 LDS overlay) + store ----------------
    float* x1f = reinterpret_cast<float*>(sm);   // h2 and G are dead
    #pragma unroll
    for (int nt = 0; nt < 8; nt++)
        #pragma unroll
        for (int r = 0; r < 4; r++)
            x1f[(w * 16 + quad * 4 + r) * 128 + nt * 16 + lq] = x1acc[nt][r];
    __syncthreads();
    {
        const float b2v = b2[w * 16 + lq];
        float* ob = out + (size_t)b * (TT * DDIM);
        #pragma unroll
        for (int m = 0; m < 8; m++) {
            #pragma unroll
            for (int r = 0; r < 4; r++) {
                int t2 = m * 16 + quad * 4 + r;
                ob[t2 * DDIM + w * 16 + lq] = oacc[m][r] + x1f[t2 * 128 + w * 16 + lq] + b2v;
            }
        }
    }
}

extern "C" void kernel_launch(void* const* d_in, const int* in_sizes, int n_in,
                              void* d_out, int out_size, void* d_ws, size_t ws_size,
                              hipStream_t stream) {
    const float* x    = (const float*)d_in[0];
    const float* ln1g = (const float*)d_in[1];
    const float* ln1b = (const float*)d_in[2];
    const float* Wq   = (const float*)d_in[3];
    const float* Wk   = (const float*)d_in[4];
    const float* Wv   = (const float*)d_in[5];
    const float* Wo   = (const float*)d_in[6];
    const float* bo   = (const float*)d_in[7];
    const float* ln2g = (const float*)d_in[8];
    const float* ln2b = (const float*)d_in[9];
    const float* W1   = (const float*)d_in[10];
    const float* b1   = (const float*)d_in[11];
    const float* W2   = (const float*)d_in[12];
    const float* b2   = (const float*)d_in[13];
    float* out = (float*)d_out;

    const int nblocks = in_sizes[0] / (TT * DDIM);   // B = 1024
    tblock_kernel<<<dim3(nblocks), dim3(512), 0, stream>>>(
        x, ln1g, ln1b, Wq, Wk, Wv, Wo, bo, ln2g, ln2b, W1, b1, W2, b2, out);
}

// Round 3
// 467.331 us; speedup vs baseline: 1.0417x; 1.0417x over previous
//
#include <hip/hip_runtime.h>
#include <hip/hip_bf16.h>

// TransformerBlock fused kernel for MI355X (gfx950) — v3: fit the 128-reg cap.
// Shapes: B=1024, T=128, D=128, H=4, HD=32, FF=512.
// One block per batch element; 512 threads = 8 waves; __launch_bounds__(512,4)
// -> 2 blocks/CU (LDS = 65,536 B). v2.1 spilled (~200MB scratch writes) because
// peak live regs ~130 > cap; v3 cuts ~45 regs of peak state:
//  - Per-head Q computed inside the head loop (reuses K-staging hf frags);
//    no persistent qf0..3.
//  - Deferred softmax normalization: unnormalized exp packed to bf16
//    immediately (16 u32, not 32 f32); 1/sum applied to PV output (8 mults),
//    redistributed across lanes with one shfl per row.
//  - quad_collect consumes pre-packed u32 pairs.
// Everything else as v2.1: swapped QK^T, in-register P repack, per-head
// K_h/V_h^T staging, per-head Wo partials into f32 x1acc, in-register LN2,
// XOR-swizzled 128x128 tiles, f32 epilogue overlay.
// MFMA 16x16x32 bf16. A-frag: A[m=lane&15][k=quad*8+j]; B-frag:
// B[k=quad*8+j][n=lane&15]; C/D: col=lane&15, row=quad*4+reg (learn_hip m89/m91).

typedef short bf16x8 __attribute__((ext_vector_type(8)));   // 8 bf16 in 4 VGPRs
typedef float f32x4  __attribute__((ext_vector_type(4)));
typedef unsigned short u16;
typedef unsigned int   u32;

#define TT   128
#define DDIM 128
#define FFD  512
#define KPIT 40    // K_h / bounce row pitch in u16 (80 B: 16B-aligned, 2-way banks)

// SCALE * log2(e): softmax done in exp2 domain with Q pre-scaled.
#define QSCALE 0.12751743f

#if defined(__has_builtin)
#if __has_builtin(__builtin_amdgcn_exp2f)
#define EXP2F(x) __builtin_amdgcn_exp2f(x)
#else
#define EXP2F(x) exp2f(x)
#endif
#if __has_builtin(__builtin_amdgcn_rcpf)
#define RCPF(x) __builtin_amdgcn_rcpf(x)
#else
#define RCPF(x) (1.0f / (x))
#endif
#else
#define EXP2F(x) exp2f(x)
#define RCPF(x) (1.0f / (x))
#endif

__device__ __forceinline__ u16 f2b(float f) {
    __hip_bfloat16 h = __float2bfloat16(f);   // RNE
    return __builtin_bit_cast(u16, h);
}
__device__ __forceinline__ u32 pk2(float x, float y) {
    return (u32)f2b(x) | ((u32)f2b(y) << 16);
}
__device__ __forceinline__ bf16x8 ldfrag(const u16* p) {  // LDS, 16B-aligned
    return __builtin_bit_cast(bf16x8, *reinterpret_cast<const uint4*>(p));
}
// Load 8 f32 from global, round to bf16 fragment (16B-aligned base).
__device__ __forceinline__ bf16x8 ldfrag_f32(const float* p) {
    float4 a = *reinterpret_cast<const float4*>(p);
    float4 b = *reinterpret_cast<const float4*>(p + 4);
    bf16x8 r;
    r[0] = (short)f2b(a.x); r[1] = (short)f2b(a.y);
    r[2] = (short)f2b(a.z); r[3] = (short)f2b(a.w);
    r[4] = (short)f2b(b.x); r[5] = (short)f2b(b.y);
    r[6] = (short)f2b(b.z); r[7] = (short)f2b(b.w);
    return r;
}
__device__ __forceinline__ f32x4 mfma16(bf16x8 a, bf16x8 b, f32x4 c) {
    return __builtin_amdgcn_mfma_f32_16x16x32_bf16(a, b, c, 0, 0, 0);
}
// Swizzled [128][128] bf16 tile: byte = row*256 + ((cg ^ (row&7))*16) + (col&7)*2
__device__ __forceinline__ bf16x8 ld_sw(const u16* base, int row, int cg) {
    return ldfrag(base + row * 128 + ((cg ^ (row & 7)) * 8));
}
__device__ __forceinline__ void st_sw(u16* base, int row, int col, u16 v) {
    base[row * 128 + (((col >> 3) ^ (row & 7)) * 8) + (col & 7)] = v;
}

// Cross-quad repack (packed input): pkv[i][d0] = pack(V[row][i*16+quad*4+2*d0],
// V[row][i*16+quad*4+2*d0+1]) (C-layout columns of this lane's row, bf16 pairs);
// output fr[g][j] = bf16(V[row][g*32 + quad*8 + j]) (A/B-frag layout).
// Row (= lane&15) preserved; only quad-dim moves. Derivation: col bits b4..b0;
// src lane quad=(b3,b2), dword=(b4,b1); dst lane quad=(b4,b3), dword=(b2,b1).
__device__ __forceinline__ void quad_collect_pk(const u32 (&pkv)[8][2],
                                                bf16x8 (&fr)[4], int lane) {
    const int srcA = (lane & 15) + ((lane & 16) << 1);  // lq + 32*l4'
    const int srcB = srcA + 16;
    const bool hi = (lane & 32) != 0;                   // l5'
    #pragma unroll
    for (int g = 0; g < 4; g++) {
        u32 D00 = pkv[2*g][0],     D01 = pkv[2*g][1];
        u32 D10 = pkv[2*g + 1][0], D11 = pkv[2*g + 1][1];
        u32 a00 = (u32)__shfl((int)D00, srcA);
        u32 a10 = (u32)__shfl((int)D10, srcA);
        u32 a01 = (u32)__shfl((int)D01, srcA);
        u32 a11 = (u32)__shfl((int)D11, srcA);
        u32 b00 = (u32)__shfl((int)D00, srcB);
        u32 b10 = (u32)__shfl((int)D10, srcB);
        u32 b01 = (u32)__shfl((int)D01, srcB);
        u32 b11 = (u32)__shfl((int)D11, srcB);
        uint4 q;
        q.x = hi ? a10 : a00;
        q.y = hi ? a11 : a01;
        q.z = hi ? b10 : b00;
        q.w = hi ? b11 : b01;
        fr[g] = __builtin_bit_cast(bf16x8, q);
    }
}
// Single-frag variant (one 2-tile group, e.g. one head's 32 columns).
__device__ __forceinline__ bf16x8 quad_collect1(u32 D00, u32 D01, u32 D10, u32 D11,
                                                int lane) {
    const int srcA = (lane & 15) + ((lane & 16) << 1);
    const int srcB = srcA + 16;
    const bool hi = (lane & 32) != 0;
    u32 a00 = (u32)__shfl((int)D00, srcA);
    u32 a10 = (u32)__shfl((int)D10, srcA);
    u32 a01 = (u32)__shfl((int)D01, srcA);
    u32 a11 = (u32)__shfl((int)D11, srcA);
    u32 b00 = (u32)__shfl((int)D00, srcB);
    u32 b10 = (u32)__shfl((int)D10, srcB);
    u32 b01 = (u32)__shfl((int)D01, srcB);
    u32 b11 = (u32)__shfl((int)D11, srcB);
    uint4 q;
    q.x = hi ? a10 : a00;
    q.y = hi ? a11 : a01;
    q.z = hi ? b10 : b00;
    q.w = hi ? b11 : b01;
    return __builtin_bit_cast(bf16x8, q);
}

__global__ __launch_bounds__(512, 4) void tblock_kernel(
    const float* __restrict__ x,
    const float* __restrict__ ln1g, const float* __restrict__ ln1b,
    const float* __restrict__ Wq,   const float* __restrict__ Wk, const float* __restrict__ Wv,
    const float* __restrict__ Wo,   const float* __restrict__ bo,
    const float* __restrict__ ln2g, const float* __restrict__ ln2b,
    const float* __restrict__ W1,   const float* __restrict__ b1,
    const float* __restrict__ W2,   const float* __restrict__ b2,
    float* __restrict__ out)
{
    // 65,536 B total: bufH [128][128] swizzled (hs -> h2);
    // r2: during attn {Kh [128][40], Vth [32][128] swz, bounce 8x[16][40]},
    //     during FF G [128][128] swizzled.
    // Epilogue overlays whole sm as f32[128][128] (x1 bounce).
    __shared__ __align__(16) u16 sm[32768];
    u16* bufH = sm;
    u16* r2   = sm + 16384;
    u16* Kh   = r2;                   // 128*40 = 5120 u16
    u16* Vth  = r2 + 5120;            // 32*128 = 4096 u16
    u16* bnc  = r2 + 5120 + 4096;     // 8*16*40 = 5120 u16

    const int b    = blockIdx.x;
    const int tid  = threadIdx.x;
    const int w    = tid >> 6;     // wave id 0..7 (owns t-rows [w*16, w*16+16))
    const int l    = tid & 63;
    const int lq   = l & 15;
    const int quad = l >> 4;
    const float* xb = x + (size_t)b * (TT * DDIM);

    // ---------------- P0: LN1(x) -> bufH (bf16, swizzled) ----------------
    {
        const int row = tid >> 2, part = tid & 3;
        const float* src = xb + row * DDIM + part * 32;
        float v[32];
        float s = 0.f, s2 = 0.f;
        #pragma unroll
        for (int i = 0; i < 8; i++) {
            float4 u = *reinterpret_cast<const float4*>(src + i * 4);
            v[i * 4 + 0] = u.x; v[i * 4 + 1] = u.y;
            v[i * 4 + 2] = u.z; v[i * 4 + 3] = u.w;
            s  += u.x + u.y + u.z + u.w;
            s2 += u.x * u.x + u.y * u.y + u.z * u.z + u.w * u.w;
        }
        s  += __shfl_xor(s, 1);  s2 += __shfl_xor(s2, 1);
        s  += __shfl_xor(s, 2);  s2 += __shfl_xor(s2, 2);
        float mean = s * (1.f / 128.f);
        float var  = fmaxf(s2 * (1.f / 128.f) - mean * mean, 0.f);
        float rstd = rsqrtf(var + 1e-5f);
        #pragma unroll
        for (int i = 0; i < 4; i++) {
            u32 o4[4];
            #pragma unroll
            for (int j = 0; j < 4; j++) {
                int c = part * 32 + i * 8 + 2 * j;
                float r0 = (v[i * 8 + 2 * j]     - mean) * rstd * ln1g[c]     + ln1b[c];
                float r1 = (v[i * 8 + 2 * j + 1] - mean) * rstd * ln1g[c + 1] + ln1b[c + 1];
                o4[j] = (u32)f2b(r0) | ((u32)f2b(r1) << 16);
            }
            uint4 pkv; pkv.x = o4[0]; pkv.y = o4[1]; pkv.z = o4[2]; pkv.w = o4[3];
            int g = (part * 4 + i) ^ (row & 7);
            *reinterpret_cast<uint4*>(bufH + row * 128 + g * 8) = pkv;
        }
    }
    __syncthreads();

    // x1 residual accumulator: (t = w*16+quad*4+r, d = nt*16+lq), f32.
    f32x4 x1acc[8];
    #pragma unroll
    for (int i = 0; i < 8; i++) x1acc[i] = f32x4{0, 0, 0, 0};

    // ---------------- P1: per-head attention ----------------
    #pragma unroll 1
    for (int h = 0; h < 4; h++) {
        bf16x8 qh;
        {
            bf16x8 hf[4];
            #pragma unroll
            for (int ks = 0; ks < 4; ks++) hf[ks] = ld_sw(bufH, w * 16 + lq, ks * 4 + quad);
            // --- stage K_h: [t][hd] pitch 40 (wave computes own t rows) ---
            #pragma unroll
            for (int nt2 = 0; nt2 < 2; nt2++) {
                f32x4 acc = {0, 0, 0, 0};
                #pragma unroll
                for (int ks = 0; ks < 4; ks++) {
                    bf16x8 bwk = ldfrag_f32(Wk + (h * 32 + nt2 * 16 + lq) * DDIM + ks * 32 + quad * 8);
                    acc = mfma16(hf[ks], bwk, acc);
                }
                #pragma unroll
                for (int r = 0; r < 4; r++)
                    Kh[(w * 16 + quad * 4 + r) * KPIT + nt2 * 16 + lq] = f2b(acc[r]);
            }
            // --- Q_h (pre-scaled) -> register B-frag via quad shuffle ---
            {
                u32 qpk[2][2];
                #pragma unroll
                for (int nt2 = 0; nt2 < 2; nt2++) {
                    f32x4 acc = {0, 0, 0, 0};
                    #pragma unroll
                    for (int ks = 0; ks < 4; ks++) {
                        bf16x8 aw = ldfrag_f32(Wq + (h * 32 + nt2 * 16 + lq) * DDIM + ks * 32 + quad * 8);
                        acc = mfma16(aw, hf[ks], acc);
                    }
                    qpk[nt2][0] = pk2(acc[0] * QSCALE, acc[1] * QSCALE);
                    qpk[nt2][1] = pk2(acc[2] * QSCALE, acc[3] * QSCALE);
                }
                qh = quad_collect1(qpk[0][0], qpk[0][1], qpk[1][0], qpk[1][1], l);
            }
            // --- stage V_h^T: [o32][t] swizzled (waves split o-halves x t-pairs) ---
            {
                bf16x8 af[4];
                #pragma unroll
                for (int ks = 0; ks < 4; ks++)
                    af[ks] = ldfrag_f32(Wv + (h * 32 + (w >> 2) * 16 + lq) * DDIM + ks * 32 + quad * 8);
                #pragma unroll
                for (int j2 = 0; j2 < 2; j2++) {
                    int nt = 2 * (w & 3) + j2;
                    f32x4 acc = {0, 0, 0, 0};
                    #pragma unroll
                    for (int ks = 0; ks < 4; ks++) {
                        bf16x8 bh = ld_sw(bufH, nt * 16 + lq, ks * 4 + quad);
                        acc = mfma16(af[ks], bh, acc);
                    }
                    #pragma unroll
                    for (int r = 0; r < 4; r++)
                        st_sw(Vth, (w >> 2) * 16 + quad * 4 + r, nt * 16 + lq, f2b(acc[r]));
                }
            }
        }
        __syncthreads();

        // --- S^T = mfma(K_frag, Q_frag): p[ns][r] = S[t=w16+lq][s=ns*16+quad*4+r] ---
        float p[8][4];
        #pragma unroll
        for (int ns = 0; ns < 8; ns++) {
            bf16x8 a = ldfrag(Kh + (ns * 16 + lq) * KPIT + quad * 8);
            f32x4 s4 = mfma16(a, qh, f32x4{0, 0, 0, 0});
            #pragma unroll
            for (int r = 0; r < 4; r++) p[ns][r] = s4[r];
        }
        // --- softmax, deferred normalization (exp2 domain; Q pre-scaled) ---
        const int trow = w * 16 + lq;
        float mx = -3.0e38f;
        #pragma unroll
        for (int ns = 0; ns < 8; ns++) {
            #pragma unroll
            for (int r = 0; r < 4; r++) {
                int sidx = ns * 16 + quad * 4 + r;
                mx = (sidx <= trow) ? fmaxf(mx, p[ns][r]) : mx;
            }
        }
        mx = fmaxf(mx, __shfl_xor(mx, 16));
        mx = fmaxf(mx, __shfl_xor(mx, 32));
        float sum = 0.f;
        u32 ppk[8][2];   // unnormalized exp, packed bf16 pairs
        #pragma unroll
        for (int ns = 0; ns < 8; ns++) {
            float e[4];
            #pragma unroll
            for (int r = 0; r < 4; r++) {
                int sidx = ns * 16 + quad * 4 + r;
                e[r] = (sidx <= trow) ? EXP2F(p[ns][r] - mx) : 0.f;
                sum += e[r];
            }
            ppk[ns][0] = pk2(e[0], e[1]);
            ppk[ns][1] = pk2(e[2], e[3]);
        }
        sum += __shfl_xor(sum, 16);
        sum += __shfl_xor(sum, 32);
        float inv = RCPF(sum);   // sum >= 1 (max lane contributes exp2(0)=1)

        // --- P -> A-frags in-register; attn_h = (P @ V_h) * inv ---
        bf16x8 pfr[4];
        quad_collect_pk(ppk, pfr, l);
        f32x4 av0 = {0, 0, 0, 0}, av1 = {0, 0, 0, 0};
        #pragma unroll
        for (int ks = 0; ks < 4; ks++) {
            int g8 = ((ks * 4 + quad) ^ (lq & 7)) * 8;
            av0 = mfma16(pfr[ks], ldfrag(Vth + lq * 128 + g8), av0);
            av1 = mfma16(pfr[ks], ldfrag(Vth + (16 + lq) * 128 + g8), av1);
        }
        #pragma unroll
        for (int r = 0; r < 4; r++) {
            // inv lives at lane layout t=w16+lq; av rows are t=w16+quad*4+r.
            float invr = __shfl(inv, quad * 4 + r);
            av0[r] *= invr; av1[r] *= invr;
        }
        // --- per-wave bounce (C-layout -> A-frag) + Wo_h partial into x1acc ---
        u16* bw_ = bnc + w * (16 * KPIT);
        #pragma unroll
        for (int r = 0; r < 4; r++) {
            bw_[(quad * 4 + r) * KPIT + lq]      = f2b(av0[r]);
            bw_[(quad * 4 + r) * KPIT + 16 + lq] = f2b(av1[r]);
        }
        asm volatile("s_waitcnt lgkmcnt(0)" ::: "memory");   // intra-wave LDS RAW
        __builtin_amdgcn_sched_barrier(0);
        bf16x8 pa = ldfrag(bw_ + lq * KPIT + quad * 8);
        #pragma unroll
        for (int nt = 0; nt < 8; nt++) {
            bf16x8 wo = ldfrag_f32(Wo + (nt * 16 + lq) * DDIM + h * 32 + quad * 8);
            x1acc[nt] = mfma16(pa, wo, x1acc[nt]);
        }
        __syncthreads();   // Kh/Vth consumed; next head may overwrite
    }

    // ---------------- P3: x1 = x + attn@Wo^T + bo (in regs) ----------------
    #pragma unroll
    for (int nt = 0; nt < 8; nt++) {
        float bov = bo[nt * 16 + lq];
        #pragma unroll
        for (int r = 0; r < 4; r++)
            x1acc[nt][r] += xb[(w * 16 + quad * 4 + r) * DDIM + nt * 16 + lq] + bov;
    }

    // ---------------- P4: LN2 in-register -> h2 into bufH ----------------
    {
        float s[4] = {0, 0, 0, 0}, s2[4] = {0, 0, 0, 0};
        #pragma unroll
        for (int nt = 0; nt < 8; nt++) {
            #pragma unroll
            for (int r = 0; r < 4; r++) {
                float v = x1acc[nt][r];
                s[r] += v; s2[r] += v * v;
            }
        }
        float mean_[4], rstd_[4];
        #pragma unroll
        for (int r = 0; r < 4; r++) {
            #pragma unroll
            for (int m_ = 1; m_ <= 8; m_ <<= 1) {
                s[r]  += __shfl_xor(s[r],  m_);
                s2[r] += __shfl_xor(s2[r], m_);
            }
            mean_[r] = s[r] * (1.f / 128.f);
            float var = fmaxf(s2[r] * (1.f / 128.f) - mean_[r] * mean_[r], 0.f);
            rstd_[r] = rsqrtf(var + 1e-5f);
        }
        #pragma unroll
        for (int nt = 0; nt < 8; nt++) {
            int d = nt * 16 + lq;
            float gg = ln2g[d], bb = ln2b[d];
            #pragma unroll
            for (int r = 0; r < 4; r++) {
                int t2 = w * 16 + quad * 4 + r;
                st_sw(bufH, t2, d, f2b((x1acc[nt][r] - mean_[r]) * rstd_[r] * gg + bb));
            }
        }
    }
    __syncthreads();

    // ---------------- P5: FF, register accumulation over f-chunks ----------------
    f32x4 oacc[8];
    #pragma unroll
    for (int i = 0; i < 8; i++) oacc[i] = f32x4{0, 0, 0, 0};

    #pragma unroll 1
    for (int fc = 0; fc < 4; fc++) {
        const int fbase = fc * 128;
        // G = relu(h2 @ W1c^T + b1) -> r2 (swizzled)
        bf16x8 wf1[4];
        #pragma unroll
        for (int ks = 0; ks < 4; ks++)
            wf1[ks] = ldfrag_f32(W1 + (fbase + w * 16 + lq) * DDIM + ks * 32 + quad * 8);
        const float b1v = b1[fbase + w * 16 + lq];
        #pragma unroll
        for (int m = 0; m < 8; m++) {
            f32x4 acc = {0, 0, 0, 0};
            #pragma unroll
            for (int ks = 0; ks < 4; ks++)
                acc = mfma16(ld_sw(bufH, m * 16 + lq, ks * 4 + quad), wf1[ks], acc);
            #pragma unroll
            for (int r = 0; r < 4; r++) {
                int t2 = m * 16 + quad * 4 + r;
                float gv = acc[r] + b1v;
                gv = gv > 0.f ? gv : 0.f;
                st_sw(r2, t2, w * 16 + lq, f2b(gv));
            }
        }
        __syncthreads();
        // oacc += G @ W2c^T  (wave owns d-cols w*16..)
        bf16x8 wf2[4];
        #pragma unroll
        for (int ks = 0; ks < 4; ks++)
            wf2[ks] = ldfrag_f32(W2 + (w * 16 + lq) * FFD + fbase + ks * 32 + quad * 8);
        #pragma unroll
        for (int m = 0; m < 8; m++) {
            #pragma unroll
            for (int ks = 0; ks < 4; ks++)
                oacc[m] = mfma16(ld_sw(r2, m * 16 + lq, ks * 4 + quad), wf2[ks], oacc[m]);
        }
        __syncthreads();
    }

    // ---------------- P6: x1 layout bounce (f32 LDS overlay) + store ----------------
    float* x1f = reinterpret_cast<float*>(sm);   // h2 and G are dead
    #pragma unroll
    for (int nt = 0; nt < 8; nt++)
        #pragma unroll
        for (int r = 0; r < 4; r++)
            x1f[(w * 16 + quad * 4 + r) * 128 + nt * 16 + lq] = x1acc[nt][r];
    __syncthreads();
    {
        const float b2v = b2[w * 16 + lq];
        float* ob = out + (size_t)b * (TT * DDIM);
        #pragma unroll
        for (int m = 0; m < 8; m++) {
            #pragma unroll
            for (int r = 0; r < 4; r++) {
                int t2 = m * 16 + quad * 4 + r;
                ob[t2 * DDIM + w * 16 + lq] = oacc[m][r] + x1f[t2 * 128 + w * 16 + lq] + b2v;
            }
        }
    }
}

extern "C" void kernel_launch(void* const* d_in, const int* in_sizes, int n_in,
                              void* d_out, int out_size, void* d_ws, size_t ws_size,
                              hipStream_t stream) {
    const float* x    = (const float*)d_in[0];
    const float* ln1g = (const float*)d_in[1];
    const float* ln1b = (const float*)d_in[2];
    const float* Wq   = (const float*)d_in[3];
    const float* Wk   = (const float*)d_in[4];
    const float* Wv   = (const float*)d_in[5];
    const float* Wo   = (const float*)d_in[6];
    const float* bo   = (const float*)d_in[7];
    const float* ln2g = (const float*)d_in[8];
    const float* ln2b = (const float*)d_in[9];
    const float* W1   = (const float*)d_in[10];
    const float* b1   = (const float*)d_in[11];
    const float* W2   = (const float*)d_in[12];
    const float* b2   = (const float*)d_in[13];
    float* out = (float*)d_out;

    const int nblocks = in_sizes[0] / (TT * DDIM);   // B = 1024
    tblock_kernel<<<dim3(nblocks), dim3(512), 0, stream>>>(
        x, ln1g, ln1b, Wq, Wk, Wv, Wo, bo, ln2g, ln2b, W1, b1, W2, b2, out);
}